// Round 3
// baseline (349.252 us; speedup 1.0000x reference)
//
#include <hip/hip_runtime.h>
#include <hip/hip_bf16.h>

#define BB 2
#define NN 2048
#define DD 128
#define HH 8
#define OUTD 256
#define SCALE 0.022097086912079612f   // 1/sqrt(2048)

typedef __bf16 bf16x8 __attribute__((ext_vector_type(8)));
typedef float f32x4 __attribute__((ext_vector_type(4)));
typedef _Float16 f16x4 __attribute__((ext_vector_type(4)));
typedef unsigned short u16x8 __attribute__((ext_vector_type(8)));

__device__ __forceinline__ unsigned short f2bf(float f) {
    union { float f; unsigned int u; } v; v.f = f;
    unsigned int r = (v.u + 0x7FFFu + ((v.u >> 16) & 1u)) >> 16;
    return (unsigned short)r;
}
__device__ __forceinline__ float bf2f(unsigned short s) {
    union { unsigned int u; float f; } v; v.u = ((unsigned int)s) << 16;
    return v.f;
}
// async global->LDS, 16 B per lane; lds dst = wave-uniform base + lane*16
__device__ __forceinline__ void gl_lds16(const unsigned short* g, unsigned short* l) {
    __builtin_amdgcn_global_load_lds(
        (const __attribute__((address_space(1))) unsigned int*)g,
        (__attribute__((address_space(3))) unsigned int*)l,
        16, 0, 0);
}

// ---------------- prep: bf16 casts + weight transposes ----------------
__global__ void prep_kernel(const float* __restrict__ X,
                            const float* __restrict__ Wq,
                            const float* __restrict__ Wk,
                            const float* __restrict__ Wv,
                            const float* __restrict__ Wout,
                            unsigned short* __restrict__ Xb,     // [B][N][D]
                            unsigned short* __restrict__ WT,     // [3][H][e][d]
                            unsigned short* __restrict__ WoutT)  // [OUT][H*D]
{
    const int NX  = BB * NN * DD;        // 524288
    const int NW  = 3 * HH * DD * DD;    // 393216
    const int NWO = (HH * DD) * OUTD;    // 262144
    int idx = blockIdx.x * blockDim.x + threadIdx.x;
    if (idx < NX) {
        Xb[idx] = f2bf(X[idx]);
    } else if (idx < NX + NW) {
        int i = idx - NX;
        int mat = i / (HH * DD * DD);
        int r   = i % (HH * DD * DD);
        int h = r / (DD * DD);
        int j = r % (DD * DD);
        int e = j / DD;
        int d = j % DD;
        const float* Wm = (mat == 0) ? Wq : ((mat == 1) ? Wk : Wv);
        WT[i] = f2bf(Wm[h * DD * DD + d * DD + e]);
    } else if (idx < NX + NW + NWO) {
        int i = idx - NX - NW;
        int o = i / (HH * DD);
        int k = i % (HH * DD);
        WoutT[i] = f2bf(Wout[k * OUTD + o]);
    }
}

// ---------------- adjsum: nodeadj.sum(-1) -> bf16, PERMUTED for attn vector loads ----
// Within each 128-key group, key k stored at position (k&15)*8 + ((k>>5)&3)*2 + ((k>>4)&1)
// so attn lane m reads its 8 values for 4 consecutive 32-key tiles as one dwordx4.
__global__ void adjsum_kernel(const float4* __restrict__ adj, unsigned short* __restrict__ s) {
    int idx = blockIdx.x * blockDim.x + threadIdx.x;  // B*N*N threads
    float4 a = adj[idx];
    int k = idx & (NN - 1);
    int p = (k & ~127) + ((k & 15) << 3) + (((k >> 5) & 3) << 1) + ((k >> 4) & 1);
    s[(idx & ~(NN - 1)) | p] = f2bf((a.x + a.y) + (a.z + a.w));
}

// ---------------- projections q/k/v ----------------
// grid (N/64, B*H, 3); block 256. mat: 0=Q, 1=K, 2=V(transposed output via LDS)
__global__ __launch_bounds__(256) void proj_kernel(
    const unsigned short* __restrict__ Xb,
    const unsigned short* __restrict__ WT,
    const float* __restrict__ bq, const float* __restrict__ bk, const float* __restrict__ bv,
    unsigned short* __restrict__ Qo, unsigned short* __restrict__ Ko,
    unsigned short* __restrict__ Vt)
{
    const int mat = blockIdx.z;
    const int bh  = blockIdx.y;
    const int b = bh >> 3, h = bh & 7;
    const int n0 = blockIdx.x * 64;
    const int tid = threadIdx.x;
    const int lane = tid & 63, wv = tid >> 6;
    const int m = lane & 15, quad = lane >> 4;

    __shared__ unsigned short Wlds[128 * 136];  // [e][d], pad 136; reused for V transpose

    const unsigned short* Wg = WT + ((size_t)mat * HH + h) * (DD * DD);
    #pragma unroll
    for (int i = tid; i < 128 * 16; i += 256) {
        int r = i >> 4, c = i & 15;
        *(uint4*)&Wlds[r * 136 + c * 8] = *(const uint4*)(Wg + r * 128 + c * 8);
    }

    const int row = n0 + wv * 16 + m;
    const unsigned short* Xr = Xb + ((size_t)b * NN + row) * DD;
    bf16x8 af[4];
    #pragma unroll
    for (int kc = 0; kc < 4; ++kc)
        af[kc] = *(const bf16x8*)(Xr + kc * 32 + quad * 8);

    __syncthreads();

    f32x4 acc[8];
    #pragma unroll
    for (int et = 0; et < 8; ++et) acc[et] = (f32x4){0.f, 0.f, 0.f, 0.f};

    #pragma unroll
    for (int kc = 0; kc < 4; ++kc) {
        #pragma unroll
        for (int et = 0; et < 8; ++et) {
            bf16x8 bfrg = *(const bf16x8*)&Wlds[(et * 16 + m) * 136 + kc * 32 + quad * 8];
            acc[et] = __builtin_amdgcn_mfma_f32_16x16x32_bf16(af[kc], bfrg, acc[et], 0, 0, 0);
        }
    }

    const float* bias = (mat == 0) ? bq : ((mat == 1) ? bk : bv);
    if (mat != 2) {
        #pragma unroll
        for (int et = 0; et < 8; ++et) {
            int e = et * 16 + m;
            float bb = bias[h * DD + e];
            #pragma unroll
            for (int reg = 0; reg < 4; ++reg) {
                int r = n0 + wv * 16 + quad * 4 + reg;
                unsigned short v16 = f2bf(acc[et][reg] + bb);
                if (mat == 0) Qo[((size_t)bh * NN + r) * DD + e] = v16;
                else          Ko[((size_t)bh * NN + r) * DD + e] = v16;
            }
        }
    } else {
        // V: transpose through LDS -> coalesced uint4 stores to Vt[bh][e][n]
        __syncthreads();  // everyone done with Wlds MFMA reads
        #pragma unroll
        for (int et = 0; et < 8; ++et) {
            int e = et * 16 + m;
            float bb = bias[h * DD + e];
            #pragma unroll
            for (int reg = 0; reg < 4; ++reg)
                Wlds[(wv * 16 + quad * 4 + reg) * 136 + e] = f2bf(acc[et][reg] + bb);
        }
        __syncthreads();
        const int e = tid >> 1, nh = tid & 1;
        #pragma unroll
        for (int j = 0; j < 4; ++j) {
            unsigned short tmp[8];
            #pragma unroll
            for (int kk = 0; kk < 8; ++kk)
                tmp[kk] = Wlds[(nh * 32 + j * 8 + kk) * 136 + e];
            *(uint4*)(Vt + ((size_t)bh * DD + e) * NN + n0 + nh * 32 + j * 8) = *(uint4*)tmp;
        }
    }
}

// ---------------- flash attention, split-K x2, async LDS staging ----------------
// v4: 32 q-rows per wave + vectorized adj path. The adj row-sums are stored
// permuted (see adjsum_kernel) so each lane loads one dwordx4 per row per
// 4-tile group (8 loads / 4 kt) instead of 16 scalar 2B loads per kt, and the
// group is prefetched one group (4 kt) ahead into registers.
// grid (64, 8): x = ((b*16 + qt)*2 + ks), y = h. 512 blocks, 2/CU.
// TK=32, double-buffered K/V via global_load_lds, XOR-swizzled LDS (linear dst).
__global__ __launch_bounds__(256, 2) void attn_kernel(
    const unsigned short* __restrict__ Q,
    const unsigned short* __restrict__ K,
    const unsigned short* __restrict__ Vt,
    const unsigned short* __restrict__ adjs,   // bf16 [B][N][N] (col-permuted)
    _Float16* __restrict__ Opart,              // [2][BH][N][D] fp16 partials
    float* __restrict__ Lpart)                 // [2][BH][N] fp32 partial row-sums
{
    const int x = blockIdx.x;
    const int h = blockIdx.y;
    const int ks = x & 1, qt = (x >> 1) & 15, b = x >> 5;
    const int bh = b * HH + h;
    const int q0 = qt * 128;
    const int kstart = ks * 1024;
    const int tid = threadIdx.x;
    const int lane = tid & 63, wv = tid >> 6;
    const int m = lane & 15, quad = lane >> 4;

    __shared__ unsigned short Kb[2][32 * 128];   // [key][d] swizzled, 8 KB each
    __shared__ unsigned short Vb[2][128 * 32];   // [d][key] swizzled, 8 KB each
    __shared__ unsigned short Plds[4][32 * 40];  // per-wave P (32q x 32k), pad 40
    // total 42 KB -> 2 blocks/CU (8 waves)

    const unsigned short* Kbase = K + (size_t)bh * NN * DD;
    const unsigned short* Vbase = Vt + (size_t)bh * DD * NN;

    // Q fragments for both 16-row halves (register-resident for whole kernel)
    bf16x8 qf[2][4];
    #pragma unroll
    for (int nq = 0; nq < 2; ++nq) {
        const unsigned short* Qr = Q + ((size_t)bh * NN + q0 + wv * 32 + nq * 16 + m) * DD;
        #pragma unroll
        for (int kc = 0; kc < 4; ++kc)
            qf[nq][kc] = *(const bf16x8*)(Qr + kc * 32 + quad * 8);
    }

    f32x4 o[2][8];
    #pragma unroll
    for (int nq = 0; nq < 2; ++nq)
        #pragma unroll
        for (int dt = 0; dt < 8; ++dt) o[nq][dt] = (f32x4){0.f, 0.f, 0.f, 0.f};
    float li[2][4] = {{0.f, 0.f, 0.f, 0.f}, {0.f, 0.f, 0.f, 0.f}};

    // adj: lane reads dwordx4 per row per 128-key group (permuted layout).
    // row j -> q-row offset (j>>2)*16 + (j&3); element offset m*8 within group.
    const unsigned short* Ab =
        adjs + ((size_t)(b * NN + q0 + wv * 32 + quad * 4)) * NN + kstart + m * 8;

    // staging lane decomposition
    const int kr4 = lane >> 4, kc16 = lane & 15;  // K: 4 rows x 16 chunks / instr
    const int vr16 = lane >> 2, vc4 = lane & 3;   // V: 16 rows x 4 chunks / instr

    // each wave stages K-instrs {2w,2w+1} (rows 8w..8w+7) and V-instrs {2w,2w+1} (d rows 32w..32w+31)
    #define STAGE(buf, kbase_)                                                              \
        {                                                                                   \
            _Pragma("unroll")                                                               \
            for (int j2 = 0; j2 < 2; ++j2) {                                                \
                const int j = wv * 2 + j2;                                                  \
                const int krow = j * 4 + kr4;                                               \
                gl_lds16(Kbase + (size_t)((kbase_) + krow) * DD + ((kc16 ^ (krow & 15)) * 8),\
                         &Kb[buf][j * 512]);                                                \
                const int vrow = j * 16 + vr16;                                             \
                gl_lds16(Vbase + (size_t)vrow * NN + (kbase_) + ((vc4 ^ ((vr16 >> 1) & 3)) * 8),\
                         &Vb[buf][j * 512]);                                                \
            }                                                                               \
        }

    // preload adj group 0
    u16x8 acur[8], anxt[8];
    #pragma unroll
    for (int j = 0; j < 8; ++j)
        acur[j] = *(const u16x8*)(Ab + ((j >> 2) * 16 + (j & 3)) * NN);

    STAGE(0, kstart);
    __syncthreads();   // vmcnt drain -> tile 0 ready

    for (int g = 0; g < 8; ++g) {
        // prefetch next adj group (consumed 4 kts from now)
        if (g < 7) {
            #pragma unroll
            for (int j = 0; j < 8; ++j)
                anxt[j] = *(const u16x8*)(Ab + ((j >> 2) * 16 + (j & 3)) * NN + (g + 1) * 128);
        }
        #pragma unroll
        for (int t = 0; t < 4; ++t) {
            const int kt = g * 4 + t;
            const int cb = kt & 1, nb = cb ^ 1;
            const int k0 = kstart + kt * 32;

            // unpack adj for this tile from the register group (static indices)
            float ar[2][2][4];
            #pragma unroll
            for (int j = 0; j < 8; ++j) {
                const int nq = j >> 2, reg = j & 3;
                ar[nq][0][reg] = bf2f(acur[j][t * 2 + 0]) * SCALE;
                ar[nq][1][reg] = bf2f(acur[j][t * 2 + 1]) * SCALE;
            }

            // async-stage next K/V tile (no wait here; barrier at loop end drains)
            if (kt + 1 < 32) STAGE(nb, k0 + 32);

            // QK^T : 16 MFMA, K-fragments shared across the two q-halves
            f32x4 s[2][2];
            #pragma unroll
            for (int nq = 0; nq < 2; ++nq)
                #pragma unroll
                for (int nt = 0; nt < 2; ++nt) s[nq][nt] = (f32x4){0.f, 0.f, 0.f, 0.f};
            #pragma unroll
            for (int kc = 0; kc < 4; ++kc) {
                #pragma unroll
                for (int nt = 0; nt < 2; ++nt) {
                    bf16x8 kf = *(const bf16x8*)&Kb[cb][(nt * 16 + m) * 128 + (((kc * 4 + quad) ^ m) * 8)];
                    s[0][nt] = __builtin_amdgcn_mfma_f32_16x16x32_bf16(qf[0][kc], kf, s[0][nt], 0, 0, 0);
                    s[1][nt] = __builtin_amdgcn_mfma_f32_16x16x32_bf16(qf[1][kc], kf, s[1][nt], 0, 0, 0);
                }
            }

            // p = exp(s*scale*adj)  (no max subtraction: |s*a| < ~1); software RNE pack
            #pragma unroll
            for (int nq = 0; nq < 2; ++nq) {
                #pragma unroll
                for (int nt = 0; nt < 2; ++nt) {
                    #pragma unroll
                    for (int reg = 0; reg < 4; ++reg) {
                        float p = __expf(s[nq][nt][reg] * ar[nq][nt][reg]);
                        li[nq][reg] += p;
                        Plds[wv][(nq * 16 + quad * 4 + reg) * 40 + nt * 16 + m] = f2bf(p);
                    }
                }
            }

            // P x V : 16 MFMA, V-fragments shared across the two q-halves
            bf16x8 pf[2];
            pf[0] = *(const bf16x8*)&Plds[wv][(0 * 16 + m) * 40 + quad * 8];
            pf[1] = *(const bf16x8*)&Plds[wv][(1 * 16 + m) * 40 + quad * 8];
            #pragma unroll
            for (int dt = 0; dt < 8; ++dt) {
                bf16x8 vf = *(const bf16x8*)&Vb[cb][(dt * 16 + m) * 32 + ((quad ^ ((m >> 1) & 3)) * 8)];
                o[0][dt] = __builtin_amdgcn_mfma_f32_16x16x32_bf16(pf[0], vf, o[0][dt], 0, 0, 0);
                o[1][dt] = __builtin_amdgcn_mfma_f32_16x16x32_bf16(pf[1], vf, o[1][dt], 0, 0, 0);
            }

            __syncthreads();  // readers done with cb; stage(nb) drained (vmcnt0 at barrier)
        }
        // rotate adj group buffers (static copies)
        #pragma unroll
        for (int j = 0; j < 8; ++j) acur[j] = anxt[j];
    }
    #undef STAGE

    #pragma unroll
    for (int nq = 0; nq < 2; ++nq) {
        // partial row-sums: reduce li across the 16 lanes of each row group
        #pragma unroll
        for (int reg = 0; reg < 4; ++reg) {
            float t = li[nq][reg];
            t += __shfl_xor(t, 1);
            t += __shfl_xor(t, 2);
            t += __shfl_xor(t, 4);
            t += __shfl_xor(t, 8);
            li[nq][reg] = t;
        }
        const int rbase = q0 + wv * 32 + nq * 16 + quad * 4;
        if (m == 0) {
            #pragma unroll
            for (int reg = 0; reg < 4; ++reg)
                Lpart[((size_t)ks * (BB * HH) + bh) * NN + rbase + reg] = li[nq][reg];
        }
        // unnormalized partial O in fp16
        #pragma unroll
        for (int reg = 0; reg < 4; ++reg) {
            const size_t obase = (((size_t)ks * (BB * HH) + bh) * NN + rbase + reg) * DD;
            #pragma unroll
            for (int dt = 0; dt < 8; ++dt)
                Opart[obase + dt * 16 + m] = (_Float16)o[nq][dt][reg];
        }
    }
}

// ---------------- combine split-K partials -> Ocat bf16 ----------------
__global__ void combine_kernel(const _Float16* __restrict__ Op,
                               const float* __restrict__ Lp,
                               unsigned short* __restrict__ Ocat)
{
    const int SPLIT_OFF = BB * HH * NN * DD;   // 4,194,304
    int t = blockIdx.x * blockDim.x + threadIdx.x;   // 1,048,576 threads
    int e0 = t * 4;
    int row = e0 >> 7;                         // bh*N + n
    float l = 1.0f / (Lp[row] + Lp[row + BB * HH * NN]);
    f16x4 a = *(const f16x4*)(Op + e0);
    f16x4 c = *(const f16x4*)(Op + SPLIT_OFF + e0);
    int bh = row >> 11, n = row & (NN - 1);
    int b = bh >> 3, h = bh & 7;
    size_t obase = ((size_t)(b * NN + n)) * (HH * DD) + h * DD + (e0 & (DD - 1));
    unsigned short u[4];
    #pragma unroll
    for (int i = 0; i < 4; ++i)
        u[i] = f2bf(((float)a[i] + (float)c[i]) * l);
    *(ushort4*)(Ocat + obase) = *(ushort4*)u;
}

// ---------------- output projection: [4096 x 1024] @ [1024 x 256] + bout ----------------
__global__ __launch_bounds__(256) void out_kernel(
    const unsigned short* __restrict__ Ocat,
    const unsigned short* __restrict__ WoutT,   // [OUT][HD]
    const float* __restrict__ bout,
    float* __restrict__ out)
{
    const int m0 = blockIdx.x * 64;
    const int c0 = blockIdx.y * 64;
    const int tid = threadIdx.x;
    const int lane = tid & 63, wv = tid >> 6;
    const int m = lane & 15, quad = lane >> 4;

    __shared__ unsigned short Wlds[64 * 136];

    f32x4 acc[4];
    #pragma unroll
    for (int nt = 0; nt < 4; ++nt) acc[nt] = (f32x4){0.f, 0.f, 0.f, 0.f};

    const unsigned short* Orow = Ocat + (size_t)(m0 + wv * 16 + m) * (HH * DD);

    for (int kc = 0; kc < 8; ++kc) {
        #pragma unroll
        for (int i = tid; i < 64 * 16; i += 256) {
            int r = i >> 4, c = i & 15;
            *(uint4*)&Wlds[r * 136 + c * 8] =
                *(const uint4*)(WoutT + (size_t)(c0 + r) * (HH * DD) + kc * 128 + c * 8);
        }
        __syncthreads();
        #pragma unroll
        for (int j = 0; j < 4; ++j) {
            bf16x8 afr = *(const bf16x8*)(Orow + kc * 128 + j * 32 + quad * 8);
            #pragma unroll
            for (int nt = 0; nt < 4; ++nt) {
                bf16x8 bfr = *(const bf16x8*)&Wlds[(nt * 16 + m) * 136 + j * 32 + quad * 8];
                acc[nt] = __builtin_amdgcn_mfma_f32_16x16x32_bf16(afr, bfr, acc[nt], 0, 0, 0);
            }
        }
        __syncthreads();
    }

    #pragma unroll
    for (int nt = 0; nt < 4; ++nt) {
        int oc = c0 + nt * 16 + m;
        float bb = bout[oc];
        #pragma unroll
        for (int reg = 0; reg < 4; ++reg) {
            int r = m0 + wv * 16 + quad * 4 + reg;
            out[(size_t)r * OUTD + oc] = acc[nt][reg] + bb;
        }
    }
}

extern "C" void kernel_launch(void* const* d_in, const int* in_sizes, int n_in,
                              void* d_out, int out_size, void* d_ws, size_t ws_size,
                              hipStream_t stream)
{
    const float* X    = (const float*)d_in[0];
    const float* adj  = (const float*)d_in[1];
    const float* Wq   = (const float*)d_in[2];
    const float* bq   = (const float*)d_in[3];
    const float* Wk   = (const float*)d_in[4];
    const float* bk   = (const float*)d_in[5];
    const float* Wv   = (const float*)d_in[6];
    const float* bv   = (const float*)d_in[7];
    const float* Wout = (const float*)d_in[8];
    const float* bout = (const float*)d_in[9];
    float* out = (float*)d_out;

    char* ws = (char*)d_ws;
    unsigned short* Xb    = (unsigned short*)(ws);             // 1,048,576 B (dead after proj)
    unsigned short* WT    = (unsigned short*)(ws + 1048576);   //   786,432 B (dead after proj)
    unsigned short* WoutT = (unsigned short*)(ws + 1835008);   //   524,288 B
    unsigned short* Q     = (unsigned short*)(ws + 2359296);   // 8,388,608 B
    unsigned short* Kp    = (unsigned short*)(ws + 10747904);  // 8,388,608 B
    unsigned short* Vt    = (unsigned short*)(ws + 19136512);  // 8,388,608 B
    unsigned short* Ocat  = (unsigned short*)(ws + 27525120);  // 8,388,608 B
    unsigned short* AsumB = (unsigned short*)(ws + 35913728);  // 16,777,216 B
    _Float16*       Opart = (_Float16*)(ws + 52690944);        // 16,777,216 B (ends 69,468,160)
    float*          Lpart = (float*)(ws);                      // 262,144 B, reuses dead Xb region

    prep_kernel<<<4608, 256, 0, stream>>>(X, Wq, Wk, Wv, Wout, Xb, WT, WoutT);
    adjsum_kernel<<<(BB * NN * NN) / 256, 256, 0, stream>>>((const float4*)adj, AsumB);
    proj_kernel<<<dim3(NN / 64, BB * HH, 3), 256, 0, stream>>>(Xb, WT, bq, bk, bv, Q, Kp, Vt);
    attn_kernel<<<dim3(64, HH), 256, 0, stream>>>(Q, Kp, Vt, AsumB, Opart, Lpart);
    combine_kernel<<<(BB * HH * NN * DD / 4) / 256, 256, 0, stream>>>(Opart, Lpart, Ocat);
    out_kernel<<<dim3((BB * NN) / 64, OUTD / 64), 256, 0, stream>>>(Ocat, WoutT, bout, out);
}

// Round 4
// 328.557 us; speedup vs baseline: 1.0630x; 1.0630x over previous
//
#include <hip/hip_runtime.h>
#include <hip/hip_bf16.h>

#define BB 2
#define NN 2048
#define DD 128
#define HH 8
#define OUTD 256
#define SCALE 0.022097086912079612f   // 1/sqrt(2048)

typedef __bf16 bf16x8 __attribute__((ext_vector_type(8)));
typedef float f32x4 __attribute__((ext_vector_type(4)));
typedef _Float16 f16x4 __attribute__((ext_vector_type(4)));
typedef unsigned short u16x8 __attribute__((ext_vector_type(8)));

__device__ __forceinline__ unsigned short f2bf(float f) {
    union { float f; unsigned int u; } v; v.f = f;
    unsigned int r = (v.u + 0x7FFFu + ((v.u >> 16) & 1u)) >> 16;
    return (unsigned short)r;
}
__device__ __forceinline__ float bf2f(unsigned short s) {
    union { unsigned int u; float f; } v; v.u = ((unsigned int)s) << 16;
    return v.f;
}
// async global->LDS, 16 B per lane; lds dst = wave-uniform base + lane*16
__device__ __forceinline__ void gl_lds16(const unsigned short* g, unsigned short* l) {
    __builtin_amdgcn_global_load_lds(
        (const __attribute__((address_space(1))) unsigned int*)g,
        (__attribute__((address_space(3))) unsigned int*)l,
        16, 0, 0);
}

// ---------------- prep: bf16 casts + weight transposes ----------------
__global__ void prep_kernel(const float* __restrict__ X,
                            const float* __restrict__ Wq,
                            const float* __restrict__ Wk,
                            const float* __restrict__ Wv,
                            const float* __restrict__ Wout,
                            unsigned short* __restrict__ Xb,     // [B][N][D]
                            unsigned short* __restrict__ WT,     // [3][H][e][d]
                            unsigned short* __restrict__ WoutT)  // [OUT][H*D]
{
    const int NX  = BB * NN * DD;        // 524288
    const int NW  = 3 * HH * DD * DD;    // 393216
    const int NWO = (HH * DD) * OUTD;    // 262144
    int idx = blockIdx.x * blockDim.x + threadIdx.x;
    if (idx < NX) {
        Xb[idx] = f2bf(X[idx]);
    } else if (idx < NX + NW) {
        int i = idx - NX;
        int mat = i / (HH * DD * DD);
        int r   = i % (HH * DD * DD);
        int h = r / (DD * DD);
        int j = r % (DD * DD);
        int e = j / DD;
        int d = j % DD;
        const float* Wm = (mat == 0) ? Wq : ((mat == 1) ? Wk : Wv);
        WT[i] = f2bf(Wm[h * DD * DD + d * DD + e]);
    } else if (idx < NX + NW + NWO) {
        int i = idx - NX - NW;
        int o = i / (HH * DD);
        int k = i % (HH * DD);
        WoutT[i] = f2bf(Wout[k * OUTD + o]);
    }
}

// ---------------- adjsum: nodeadj.sum(-1) -> bf16, permuted via LDS ----------------
// Layout (within each 128-key group): key k -> pos (k&15)*8 + ((k>>5)&3)*2 + ((k>>4)&1)
// so attn lane m reads its 8 values for 4 consecutive 32-key tiles as one dwordx4.
// Permutation done in LDS; global stores stay coalesced (32 lanes x uint4).
__global__ void adjsum_kernel(const float4* __restrict__ adj, unsigned short* __restrict__ s) {
    __shared__ __align__(16) unsigned short ls[256];
    const int tid = threadIdx.x;
    const int idx = blockIdx.x * 256 + tid;      // block spans 256 consecutive keys (2 groups)
    float4 a = adj[idx];
    const int k = tid & 127;
    const int p = ((k & 15) << 3) + (((k >> 5) & 3) << 1) + ((k >> 4) & 1);
    ls[(tid & 128) + p] = f2bf((a.x + a.y) + (a.z + a.w));
    __syncthreads();
    if (tid < 32)
        *(uint4*)(s + (size_t)blockIdx.x * 256 + tid * 8) = *(const uint4*)&ls[tid * 8];
}

// ---------------- projections q/k/v ----------------
// grid (N/64, B*H, 3); block 256. mat: 0=Q, 1=K, 2=V(transposed output via LDS)
__global__ __launch_bounds__(256) void proj_kernel(
    const unsigned short* __restrict__ Xb,
    const unsigned short* __restrict__ WT,
    const float* __restrict__ bq, const float* __restrict__ bk, const float* __restrict__ bv,
    unsigned short* __restrict__ Qo, unsigned short* __restrict__ Ko,
    unsigned short* __restrict__ Vt)
{
    const int mat = blockIdx.z;
    const int bh  = blockIdx.y;
    const int b = bh >> 3, h = bh & 7;
    const int n0 = blockIdx.x * 64;
    const int tid = threadIdx.x;
    const int lane = tid & 63, wv = tid >> 6;
    const int m = lane & 15, quad = lane >> 4;

    __shared__ unsigned short Wlds[128 * 136];  // [e][d], pad 136; reused for V transpose

    const unsigned short* Wg = WT + ((size_t)mat * HH + h) * (DD * DD);
    #pragma unroll
    for (int i = tid; i < 128 * 16; i += 256) {
        int r = i >> 4, c = i & 15;
        *(uint4*)&Wlds[r * 136 + c * 8] = *(const uint4*)(Wg + r * 128 + c * 8);
    }

    const int row = n0 + wv * 16 + m;
    const unsigned short* Xr = Xb + ((size_t)b * NN + row) * DD;
    bf16x8 af[4];
    #pragma unroll
    for (int kc = 0; kc < 4; ++kc)
        af[kc] = *(const bf16x8*)(Xr + kc * 32 + quad * 8);

    __syncthreads();

    f32x4 acc[8];
    #pragma unroll
    for (int et = 0; et < 8; ++et) acc[et] = (f32x4){0.f, 0.f, 0.f, 0.f};

    #pragma unroll
    for (int kc = 0; kc < 4; ++kc) {
        #pragma unroll
        for (int et = 0; et < 8; ++et) {
            bf16x8 bfrg = *(const bf16x8*)&Wlds[(et * 16 + m) * 136 + kc * 32 + quad * 8];
            acc[et] = __builtin_amdgcn_mfma_f32_16x16x32_bf16(af[kc], bfrg, acc[et], 0, 0, 0);
        }
    }

    const float* bias = (mat == 0) ? bq : ((mat == 1) ? bk : bv);
    if (mat != 2) {
        #pragma unroll
        for (int et = 0; et < 8; ++et) {
            int e = et * 16 + m;
            float bb = bias[h * DD + e];
            #pragma unroll
            for (int reg = 0; reg < 4; ++reg) {
                int r = n0 + wv * 16 + quad * 4 + reg;
                unsigned short v16 = f2bf(acc[et][reg] + bb);
                if (mat == 0) Qo[((size_t)bh * NN + r) * DD + e] = v16;
                else          Ko[((size_t)bh * NN + r) * DD + e] = v16;
            }
        }
    } else {
        // V: transpose through LDS -> coalesced uint4 stores to Vt[bh][e][n]
        __syncthreads();  // everyone done with Wlds MFMA reads
        #pragma unroll
        for (int et = 0; et < 8; ++et) {
            int e = et * 16 + m;
            float bb = bias[h * DD + e];
            #pragma unroll
            for (int reg = 0; reg < 4; ++reg)
                Wlds[(wv * 16 + quad * 4 + reg) * 136 + e] = f2bf(acc[et][reg] + bb);
        }
        __syncthreads();
        const int e = tid >> 1, nh = tid & 1;
        #pragma unroll
        for (int j = 0; j < 4; ++j) {
            unsigned short tmp[8];
            #pragma unroll
            for (int kk = 0; kk < 8; ++kk)
                tmp[kk] = Wlds[(nh * 32 + j * 8 + kk) * 136 + e];
            *(uint4*)(Vt + ((size_t)bh * DD + e) * NN + n0 + nh * 32 + j * 8) = *(uint4*)tmp;
        }
    }
}

// ---------------- flash attention, split-K x2, async LDS staging ----------------
// v5: back to 16 q-rows/wave, 4 blocks/CU (R0 geometry — best TLP for the
// latency-bound regime the R3 counters showed), keeping R3's vectorized adj
// path: 4 x dwordx4 per lane per 4-kt group (permuted AsumB layout), loaded at
// group top and covered by the QK^T MFMAs.
// grid (128, 8): x = ((b*32 + qt)*2 + ks), y = h (h-siblings share XCD).
// block 256 = 4 waves x 16 q-rows. TK=32, double-buffered K/V via
// global_load_lds, XOR-swizzled LDS (linear dst, conflict-free reads).
__global__ __launch_bounds__(256, 4) void attn_kernel(
    const unsigned short* __restrict__ Q,
    const unsigned short* __restrict__ K,
    const unsigned short* __restrict__ Vt,
    const unsigned short* __restrict__ adjs,   // bf16 [B][N][N] (col-permuted)
    _Float16* __restrict__ Opart,              // [2][BH][N][D] fp16 partials
    float* __restrict__ Lpart)                 // [2][BH][N] fp32 partial row-sums
{
    const int x = blockIdx.x;
    const int h = blockIdx.y;
    const int ks = x & 1, qt = (x >> 1) & 31, b = x >> 6;
    const int bh = b * HH + h;
    const int q0 = qt * 64;
    const int kstart = ks * 1024;
    const int tid = threadIdx.x;
    const int lane = tid & 63, wv = tid >> 6;
    const int m = lane & 15, quad = lane >> 4;

    __shared__ unsigned short Kb[2][32 * 128];   // [key][d] swizzled, 8 KB each
    __shared__ unsigned short Vb[2][128 * 32];   // [d][key] swizzled, 8 KB each
    __shared__ unsigned short Plds[4][16 * 40];  // per-wave P, pad 40 -> 5 KB
    // total 37.9 KB -> 4 blocks/CU

    const unsigned short* Kbase = K + (size_t)bh * NN * DD;
    const unsigned short* Vbase = Vt + (size_t)bh * DD * NN;

    // Q fragments (register-resident for whole kernel)
    const int qrow = q0 + wv * 16 + m;
    const unsigned short* Qr = Q + ((size_t)bh * NN + qrow) * DD;
    bf16x8 qf[4];
    #pragma unroll
    for (int kc = 0; kc < 4; ++kc)
        qf[kc] = *(const bf16x8*)(Qr + kc * 32 + quad * 8);

    f32x4 o[8];
    #pragma unroll
    for (int dt = 0; dt < 8; ++dt) o[dt] = (f32x4){0.f, 0.f, 0.f, 0.f};
    float li[4] = {0.f, 0.f, 0.f, 0.f};

    // adj: lane reads dwordx4 per row per 128-key group (permuted layout).
    const unsigned short* Ab =
        adjs + ((size_t)(b * NN + q0 + wv * 16 + quad * 4)) * NN + kstart + m * 8;

    // staging lane decomposition
    const int kr4 = lane >> 4, kc16 = lane & 15;  // K: 4 rows x 16 chunks / instr
    const int vr16 = lane >> 2, vc4 = lane & 3;   // V: 16 rows x 4 chunks / instr

    // each wave stages K-instrs {2w,2w+1} (rows 8w..8w+7) and V-instrs {2w,2w+1} (d rows 32w..32w+31)
    #define STAGE(buf, kbase_)                                                              \
        {                                                                                   \
            _Pragma("unroll")                                                               \
            for (int j2 = 0; j2 < 2; ++j2) {                                                \
                const int j = wv * 2 + j2;                                                  \
                const int krow = j * 4 + kr4;                                               \
                gl_lds16(Kbase + (size_t)((kbase_) + krow) * DD + ((kc16 ^ (krow & 15)) * 8),\
                         &Kb[buf][j * 512]);                                                \
                const int vrow = j * 16 + vr16;                                             \
                gl_lds16(Vbase + (size_t)vrow * NN + (kbase_) + ((vc4 ^ ((vr16 >> 1) & 3)) * 8),\
                         &Vb[buf][j * 512]);                                                \
            }                                                                               \
        }

    STAGE(0, kstart);
    __syncthreads();   // vmcnt drain -> tile 0 ready

    u16x8 acur[4];

    for (int g = 0; g < 8; ++g) {
        // load adj group g (4 x dwordx4); consumed after QK^T of t=0 -> latency covered
        #pragma unroll
        for (int j = 0; j < 4; ++j)
            acur[j] = *(const u16x8*)(Ab + (size_t)j * NN + g * 128);

        #pragma unroll
        for (int t = 0; t < 4; ++t) {
            const int kt = g * 4 + t;
            const int cb = kt & 1, nb = cb ^ 1;
            const int k0 = kstart + kt * 32;

            // async-stage next tile (no wait here; barrier at loop end drains)
            if (kt + 1 < 32) STAGE(nb, k0 + 32);

            // QK^T : 8 MFMA
            f32x4 s[2];
            s[0] = (f32x4){0.f, 0.f, 0.f, 0.f};
            s[1] = (f32x4){0.f, 0.f, 0.f, 0.f};
            #pragma unroll
            for (int kc = 0; kc < 4; ++kc) {
                #pragma unroll
                for (int nt = 0; nt < 2; ++nt) {
                    bf16x8 kf = *(const bf16x8*)&Kb[cb][(nt * 16 + m) * 128 + (((kc * 4 + quad) ^ m) * 8)];
                    s[nt] = __builtin_amdgcn_mfma_f32_16x16x32_bf16(qf[kc], kf, s[nt], 0, 0, 0);
                }
            }

            // p = exp(s*scale*adj)  (no max subtraction: |s*a| < ~1)
            #pragma unroll
            for (int nt = 0; nt < 2; ++nt) {
                #pragma unroll
                for (int reg = 0; reg < 4; ++reg) {
                    float ar = bf2f(acur[reg][t * 2 + nt]) * SCALE;
                    float p = __expf(s[nt][reg] * ar);
                    li[reg] += p;
                    Plds[wv][(quad * 4 + reg) * 40 + nt * 16 + m] = f2bf(p);
                }
            }

            // P x V : 8 MFMA (K=32 covers full tile)
            bf16x8 pf = *(const bf16x8*)&Plds[wv][m * 40 + quad * 8];
            #pragma unroll
            for (int dt = 0; dt < 8; ++dt) {
                bf16x8 vf = *(const bf16x8*)&Vb[cb][(dt * 16 + m) * 32 + ((quad ^ ((m >> 1) & 3)) * 8)];
                o[dt] = __builtin_amdgcn_mfma_f32_16x16x32_bf16(pf, vf, o[dt], 0, 0, 0);
            }

            __syncthreads();  // readers done with cb; stage(nb) drained (vmcnt0 at barrier)
        }
    }
    #undef STAGE

    // partial row-sums: reduce li across the 16 lanes of each row group
    #pragma unroll
    for (int reg = 0; reg < 4; ++reg) {
        float t = li[reg];
        t += __shfl_xor(t, 1);
        t += __shfl_xor(t, 2);
        t += __shfl_xor(t, 4);
        t += __shfl_xor(t, 8);
        li[reg] = t;
    }
    const int rbase = q0 + wv * 16 + quad * 4;
    if (m == 0) {
        #pragma unroll
        for (int reg = 0; reg < 4; ++reg)
            Lpart[((size_t)ks * (BB * HH) + bh) * NN + rbase + reg] = li[reg];
    }
    // unnormalized partial O in fp16
    #pragma unroll
    for (int reg = 0; reg < 4; ++reg) {
        const size_t obase = (((size_t)ks * (BB * HH) + bh) * NN + rbase + reg) * DD;
        #pragma unroll
        for (int dt = 0; dt < 8; ++dt)
            Opart[obase + dt * 16 + m] = (_Float16)o[dt][reg];
    }
}

// ---------------- combine split-K partials -> Ocat bf16 ----------------
__global__ void combine_kernel(const _Float16* __restrict__ Op,
                               const float* __restrict__ Lp,
                               unsigned short* __restrict__ Ocat)
{
    const int SPLIT_OFF = BB * HH * NN * DD;   // 4,194,304
    int t = blockIdx.x * blockDim.x + threadIdx.x;   // 1,048,576 threads
    int e0 = t * 4;
    int row = e0 >> 7;                         // bh*N + n
    float l = 1.0f / (Lp[row] + Lp[row + BB * HH * NN]);
    f16x4 a = *(const f16x4*)(Op + e0);
    f16x4 c = *(const f16x4*)(Op + SPLIT_OFF + e0);
    int bh = row >> 11, n = row & (NN - 1);
    int b = bh >> 3, h = bh & 7;
    size_t obase = ((size_t)(b * NN + n)) * (HH * DD) + h * DD + (e0 & (DD - 1));
    unsigned short u[4];
    #pragma unroll
    for (int i = 0; i < 4; ++i)
        u[i] = f2bf(((float)a[i] + (float)c[i]) * l);
    *(ushort4*)(Ocat + obase) = *(ushort4*)u;
}

// ---------------- output projection: [4096 x 1024] @ [1024 x 256] + bout ----------------
__global__ __launch_bounds__(256) void out_kernel(
    const unsigned short* __restrict__ Ocat,
    const unsigned short* __restrict__ WoutT,   // [OUT][HD]
    const float* __restrict__ bout,
    float* __restrict__ out)
{
    const int m0 = blockIdx.x * 64;
    const int c0 = blockIdx.y * 64;
    const int tid = threadIdx.x;
    const int lane = tid & 63, wv = tid >> 6;
    const int m = lane & 15, quad = lane >> 4;

    __shared__ unsigned short Wlds[64 * 136];

    f32x4 acc[4];
    #pragma unroll
    for (int nt = 0; nt < 4; ++nt) acc[nt] = (f32x4){0.f, 0.f, 0.f, 0.f};

    const unsigned short* Orow = Ocat + (size_t)(m0 + wv * 16 + m) * (HH * DD);

    for (int kc = 0; kc < 8; ++kc) {
        #pragma unroll
        for (int i = tid; i < 64 * 16; i += 256) {
            int r = i >> 4, c = i & 15;
            *(uint4*)&Wlds[r * 136 + c * 8] =
                *(const uint4*)(WoutT + (size_t)(c0 + r) * (HH * DD) + kc * 128 + c * 8);
        }
        __syncthreads();
        #pragma unroll
        for (int j = 0; j < 4; ++j) {
            bf16x8 afr = *(const bf16x8*)(Orow + kc * 128 + j * 32 + quad * 8);
            #pragma unroll
            for (int nt = 0; nt < 4; ++nt) {
                bf16x8 bfr = *(const bf16x8*)&Wlds[(nt * 16 + m) * 136 + j * 32 + quad * 8];
                acc[nt] = __builtin_amdgcn_mfma_f32_16x16x32_bf16(afr, bfr, acc[nt], 0, 0, 0);
            }
        }
        __syncthreads();
    }

    #pragma unroll
    for (int nt = 0; nt < 4; ++nt) {
        int oc = c0 + nt * 16 + m;
        float bb = bout[oc];
        #pragma unroll
        for (int reg = 0; reg < 4; ++reg) {
            int r = m0 + wv * 16 + quad * 4 + reg;
            out[(size_t)r * OUTD + oc] = acc[nt][reg] + bb;
        }
    }
}

extern "C" void kernel_launch(void* const* d_in, const int* in_sizes, int n_in,
                              void* d_out, int out_size, void* d_ws, size_t ws_size,
                              hipStream_t stream)
{
    const float* X    = (const float*)d_in[0];
    const float* adj  = (const float*)d_in[1];
    const float* Wq   = (const float*)d_in[2];
    const float* bq   = (const float*)d_in[3];
    const float* Wk   = (const float*)d_in[4];
    const float* bk   = (const float*)d_in[5];
    const float* Wv   = (const float*)d_in[6];
    const float* bv   = (const float*)d_in[7];
    const float* Wout = (const float*)d_in[8];
    const float* bout = (const float*)d_in[9];
    float* out = (float*)d_out;

    char* ws = (char*)d_ws;
    unsigned short* Xb    = (unsigned short*)(ws);             // 1,048,576 B (dead after proj)
    unsigned short* WT    = (unsigned short*)(ws + 1048576);   //   786,432 B (dead after proj)
    unsigned short* WoutT = (unsigned short*)(ws + 1835008);   //   524,288 B
    unsigned short* Q     = (unsigned short*)(ws + 2359296);   // 8,388,608 B
    unsigned short* Kp    = (unsigned short*)(ws + 10747904);  // 8,388,608 B
    unsigned short* Vt    = (unsigned short*)(ws + 19136512);  // 8,388,608 B
    unsigned short* Ocat  = (unsigned short*)(ws + 27525120);  // 8,388,608 B
    unsigned short* AsumB = (unsigned short*)(ws + 35913728);  // 16,777,216 B
    _Float16*       Opart = (_Float16*)(ws + 52690944);        // 16,777,216 B (ends 69,468,160)
    float*          Lpart = (float*)(ws);                      // 262,144 B, reuses dead Xb region

    prep_kernel<<<4608, 256, 0, stream>>>(X, Wq, Wk, Wv, Wout, Xb, WT, WoutT);
    adjsum_kernel<<<(BB * NN * NN) / 256, 256, 0, stream>>>((const float4*)adj, AsumB);
    proj_kernel<<<dim3(NN / 64, BB * HH, 3), 256, 0, stream>>>(Xb, WT, bq, bk, bv, Q, Kp, Vt);
    attn_kernel<<<dim3(128, HH), 256, 0, stream>>>(Q, Kp, Vt, AsumB, Opart, Lpart);
    combine_kernel<<<(BB * HH * NN * DD / 4) / 256, 256, 0, stream>>>(Opart, Lpart, Ocat);
    out_kernel<<<dim3((BB * NN) / 64, OUTD / 64), 256, 0, stream>>>(Ocat, WoutT, bout, out);
}

// Round 5
// 326.222 us; speedup vs baseline: 1.0706x; 1.0072x over previous
//
#include <hip/hip_runtime.h>
#include <hip/hip_bf16.h>

#define BB 2
#define NN 2048
#define DD 128
#define HH 8
#define OUTD 256
#define SCALE 0.022097086912079612f  // 1/sqrt(2048)

typedef __bf16 bf16x8 __attribute__((ext_vector_type(8)));
typedef float f32x4 __attribute__((ext_vector_type(4)));
typedef _Float16 f16x4 __attribute__((ext_vector_type(4)));

__device__ __forceinline__ unsigned short f2bf(float f) {
    union { float f; unsigned int u; } v; v.f = f;
    unsigned int r = (v.u + 0x7FFFu + ((v.u >> 16) & 1u)) >> 16;
    return (unsigned short)r;
}
__device__ __forceinline__ float bf2f(unsigned short s) {
    union { unsigned int u; float f; } v; v.u = ((unsigned int)s) << 16;
    return v.f;
}
// async global->LDS, 16 B per lane; lds dst = wave-uniform base + lane*16
__device__ __forceinline__ void gl_lds16(const unsigned short* g, unsigned short* l) {
    __builtin_amdgcn_global_load_lds(
        (const __attribute__((address_space(1))) unsigned int*)g,
        (__attribute__((address_space(3))) unsigned int*)l,
        16, 0, 0);
}

// ---------------- prep: bf16 casts + weight transposes ----------------
__global__ void prep_kernel(const float* __restrict__ X,
                            const float* __restrict__ Wq,
                            const float* __restrict__ Wk,
                            const float* __restrict__ Wv,
                            const float* __restrict__ Wout,
                            unsigned short* __restrict__ Xb,     // [B][N][D]
                            unsigned short* __restrict__ WT,     // [3][H][e][d]
                            unsigned short* __restrict__ WoutT)  // [OUT][H*D]
{
    const int NX  = BB * NN * DD;        // 524288
    const int NW  = 3 * HH * DD * DD;    // 393216
    const int NWO = (HH * DD) * OUTD;    // 262144
    int idx = blockIdx.x * blockDim.x + threadIdx.x;
    if (idx < NX) {
        Xb[idx] = f2bf(X[idx]);
    } else if (idx < NX + NW) {
        int i = idx - NX;
        int mat = i / (HH * DD * DD);
        int r   = i % (HH * DD * DD);
        int h = r / (DD * DD);
        int j = r % (DD * DD);
        int e = j / DD;
        int d = j % DD;
        const float* Wm = (mat == 0) ? Wq : ((mat == 1) ? Wk : Wv);
        WT[i] = f2bf(Wm[h * DD * DD + d * DD + e]);
    } else if (idx < NX + NW + NWO) {
        int i = idx - NX - NW;
        int o = i / (HH * DD);
        int k = i % (HH * DD);
        WoutT[i] = f2bf(Wout[k * OUTD + o]);
    }
}

// ---------------- adjsum: nodeadj.sum(-1) -> bf16 ----------------
__global__ void adjsum_kernel(const float4* __restrict__ adj, unsigned short* __restrict__ s) {
    int idx = blockIdx.x * blockDim.x + threadIdx.x;  // B*N*N threads
    float4 a = adj[idx];
    s[idx] = f2bf((a.x + a.y) + (a.z + a.w));
}

// ---------------- projections q/k/v ----------------
// grid (N/64, B*H, 3); block 256. mat: 0=Q, 1=K, 2=V(transposed output via LDS)
__global__ __launch_bounds__(256) void proj_kernel(
    const unsigned short* __restrict__ Xb,
    const unsigned short* __restrict__ WT,
    const float* __restrict__ bq, const float* __restrict__ bk, const float* __restrict__ bv,
    unsigned short* __restrict__ Qo, unsigned short* __restrict__ Ko,
    unsigned short* __restrict__ Vt)
{
    const int mat = blockIdx.z;
    const int bh  = blockIdx.y;
    const int b = bh >> 3, h = bh & 7;
    const int n0 = blockIdx.x * 64;
    const int tid = threadIdx.x;
    const int lane = tid & 63, wv = tid >> 6;
    const int m = lane & 15, quad = lane >> 4;

    __shared__ unsigned short Wlds[128 * 136];  // [e][d], pad 136; reused for V transpose

    const unsigned short* Wg = WT + ((size_t)mat * HH + h) * (DD * DD);
    #pragma unroll
    for (int i = tid; i < 128 * 16; i += 256) {
        int r = i >> 4, c = i & 15;
        *(uint4*)&Wlds[r * 136 + c * 8] = *(const uint4*)(Wg + r * 128 + c * 8);
    }

    const int row = n0 + wv * 16 + m;
    const unsigned short* Xr = Xb + ((size_t)b * NN + row) * DD;
    bf16x8 af[4];
    #pragma unroll
    for (int kc = 0; kc < 4; ++kc)
        af[kc] = *(const bf16x8*)(Xr + kc * 32 + quad * 8);

    __syncthreads();

    f32x4 acc[8];
    #pragma unroll
    for (int et = 0; et < 8; ++et) acc[et] = (f32x4){0.f, 0.f, 0.f, 0.f};

    #pragma unroll
    for (int kc = 0; kc < 4; ++kc) {
        #pragma unroll
        for (int et = 0; et < 8; ++et) {
            bf16x8 bfrg = *(const bf16x8*)&Wlds[(et * 16 + m) * 136 + kc * 32 + quad * 8];
            acc[et] = __builtin_amdgcn_mfma_f32_16x16x32_bf16(af[kc], bfrg, acc[et], 0, 0, 0);
        }
    }

    const float* bias = (mat == 0) ? bq : ((mat == 1) ? bk : bv);
    if (mat != 2) {
        #pragma unroll
        for (int et = 0; et < 8; ++et) {
            int e = et * 16 + m;
            float bb = bias[h * DD + e];
            #pragma unroll
            for (int reg = 0; reg < 4; ++reg) {
                int r = n0 + wv * 16 + quad * 4 + reg;
                unsigned short v16 = f2bf(acc[et][reg] + bb);
                if (mat == 0) Qo[((size_t)bh * NN + r) * DD + e] = v16;
                else          Ko[((size_t)bh * NN + r) * DD + e] = v16;
            }
        }
    } else {
        // V: transpose through LDS -> coalesced uint4 stores to Vt[bh][e][n]
        __syncthreads();  // everyone done with Wlds MFMA reads
        #pragma unroll
        for (int et = 0; et < 8; ++et) {
            int e = et * 16 + m;
            float bb = bias[h * DD + e];
            #pragma unroll
            for (int reg = 0; reg < 4; ++reg)
                Wlds[(wv * 16 + quad * 4 + reg) * 136 + e] = f2bf(acc[et][reg] + bb);
        }
        __syncthreads();
        const int e = tid >> 1, nh = tid & 1;
        #pragma unroll
        for (int j = 0; j < 4; ++j) {
            unsigned short tmp[8];
            #pragma unroll
            for (int kk = 0; kk < 8; ++kk)
                tmp[kk] = Wlds[(nh * 32 + j * 8 + kk) * 136 + e];
            *(uint4*)(Vt + ((size_t)bh * DD + e) * NN + n0 + nh * 32 + j * 8) = *(uint4*)tmp;
        }
    }
}

// ---------------- flash attention, split-K x2, async LDS staging ----------------
// v6: R0 geometry (16 q-rows/wave, scalar per-kt adj loads — R3/R4's adj
// restructures both measured slower and are reverted). ONE change vs R0:
// 3-deep K/V buffering with counted s_waitcnt vmcnt(4) + raw s_barrier
// instead of __syncthreads' vmcnt(0) drain every kt (T3/T4). Stage for tile
// kt+2 issues at kt; vmcnt retires in issue order (m135), and >=4 younger
// vmem ops always separate tile-kt's stage from the kt-top wait, so
// vmcnt(4)+barrier guarantees tile kt is resident without ever draining the
// in-flight queue. Buffer written at kt was last read at kt-1; the kt-top
// barrier orders that (write-after-read safe).
// grid (128, 8): x = ((b*32 + qt)*2 + ks), y = h. block 256 = 4 waves.
// LDS 54.3 KB -> 3 blocks/CU (matches the ~12 waves/CU occupancy measured
// in R4, so no TLP loss vs 2-buffer's 4 blocks).
__global__ __launch_bounds__(256, 3) void attn_kernel(
    const unsigned short* __restrict__ Q,
    const unsigned short* __restrict__ K,
    const unsigned short* __restrict__ Vt,
    const unsigned short* __restrict__ adjs,   // bf16 [B][N][N]
    _Float16* __restrict__ Opart,              // [2][BH][N][D] fp16 partials
    float* __restrict__ Lpart)                 // [2][BH][N] fp32 partial row-sums
{
    const int x = blockIdx.x;
    const int h = blockIdx.y;
    const int ks = x & 1, qt = (x >> 1) & 31, b = x >> 6;
    const int bh = b * HH + h;
    const int q0 = qt * 64;
    const int kstart = ks * 1024;
    const int tid = threadIdx.x;
    const int lane = tid & 63, wv = tid >> 6;
    const int m = lane & 15, quad = lane >> 4;

    __shared__ unsigned short Kb[3][32 * 128];   // [key][d] swizzled, 8 KB each
    __shared__ unsigned short Vb[3][128 * 32];   // [d][key] swizzled, 8 KB each
    __shared__ unsigned short Plds[4][16 * 40];  // per-wave P, pad 40 -> 5 KB
    // total 54.3 KB -> 3 blocks/CU

    const unsigned short* Kbase = K + (size_t)bh * NN * DD;
    const unsigned short* Vbase = Vt + (size_t)bh * DD * NN;

    // Q fragments (register-resident for whole kernel)
    const int qrow = q0 + wv * 16 + m;
    const unsigned short* Qr = Q + ((size_t)bh * NN + qrow) * DD;
    bf16x8 qf[4];
    #pragma unroll
    for (int kc = 0; kc < 4; ++kc)
        qf[kc] = *(const bf16x8*)(Qr + kc * 32 + quad * 8);

    f32x4 o[8];
    #pragma unroll
    for (int dt = 0; dt < 8; ++dt) o[dt] = (f32x4){0.f, 0.f, 0.f, 0.f};
    float li[4] = {0.f, 0.f, 0.f, 0.f};

    const unsigned short* Abase = adjs + ((size_t)b * NN + q0 + wv * 16 + quad * 4) * NN;

    // staging lane decomposition
    const int kr4 = lane >> 4, kc16 = lane & 15;  // K: 4 rows x 16 chunks / instr
    const int vr16 = lane >> 2, vc4 = lane & 3;   // V: 16 rows x 4 chunks / instr

    // each wave stages K-instrs {2w,2w+1} (rows 8w..8w+7) and V-instrs {2w,2w+1} (d rows 32w..32w+31)
    #define STAGE(buf, kbase_)                                                              \
        {                                                                                   \
            _Pragma("unroll")                                                               \
            for (int j2 = 0; j2 < 2; ++j2) {                                                \
                const int j = wv * 2 + j2;                                                  \
                const int krow = j * 4 + kr4;                                               \
                gl_lds16(Kbase + (size_t)((kbase_) + krow) * DD + ((kc16 ^ (krow & 15)) * 8),\
                         &Kb[buf][j * 512]);                                                \
                const int vrow = j * 16 + vr16;                                             \
                gl_lds16(Vbase + (size_t)vrow * NN + (kbase_) + ((vc4 ^ ((vr16 >> 1) & 3)) * 8),\
                         &Vb[buf][j * 512]);                                                \
            }                                                                               \
        }

    // prologue: stage tiles 0 and 1 into buffers 0 and 1 (8 loads in flight)
    STAGE(0, kstart);
    STAGE(1, kstart + 32);

    int cb = 0;  // buffer holding tile kt
    for (int kt = 0; kt < 32; ++kt) {
        const int k0 = kstart + kt * 32;

        // counted wait: tile kt's 4 stage loads are >=2 bodies old; vmcnt
        // retires oldest-first, and >=4 younger vmem ops were issued since,
        // so vmcnt(4) guarantees tile kt landed. Raw barrier (no drain)
        // publishes all waves' stages + orders prev-body reads before the
        // overwrite below.
        __builtin_amdgcn_sched_barrier(0);
        asm volatile("s_waitcnt vmcnt(4)" ::: "memory");
        __builtin_amdgcn_s_barrier();
        __builtin_amdgcn_sched_barrier(0);

        // adj (bf16) for current tile, per-lane scalar loads (consumed after QK)
        float areg[2][4];
        #pragma unroll
        for (int nt = 0; nt < 2; ++nt)
            #pragma unroll
            for (int reg = 0; reg < 4; ++reg)
                areg[nt][reg] = bf2f(Abase[(size_t)reg * NN + k0 + nt * 16 + m]) * SCALE;

        // async-stage tile kt+2 into the buffer last read at kt-1
        if (kt + 2 < 32) {
            const int sb = (cb == 0) ? 2 : cb - 1;
            STAGE(sb, k0 + 64);
        }

        // QK^T : 8 MFMA
        f32x4 s[2];
        s[0] = (f32x4){0.f, 0.f, 0.f, 0.f};
        s[1] = (f32x4){0.f, 0.f, 0.f, 0.f};
        #pragma unroll
        for (int kc = 0; kc < 4; ++kc) {
            #pragma unroll
            for (int nt = 0; nt < 2; ++nt) {
                bf16x8 kf = *(const bf16x8*)&Kb[cb][(nt * 16 + m) * 128 + (((kc * 4 + quad) ^ m) * 8)];
                s[nt] = __builtin_amdgcn_mfma_f32_16x16x32_bf16(qf[kc], kf, s[nt], 0, 0, 0);
            }
        }

        // p = exp(s*scale*adj)  (no max subtraction: |s*a| < ~1)
        #pragma unroll
        for (int nt = 0; nt < 2; ++nt) {
            #pragma unroll
            for (int reg = 0; reg < 4; ++reg) {
                float p = __expf(s[nt][reg] * areg[nt][reg]);
                li[reg] += p;
                Plds[wv][(quad * 4 + reg) * 40 + nt * 16 + m] = f2bf(p);
            }
        }

        // P x V : 8 MFMA (K=32 covers full tile; P is intra-wave, lgkm-ordered)
        bf16x8 pf = *(const bf16x8*)&Plds[wv][m * 40 + quad * 8];
        #pragma unroll
        for (int dt = 0; dt < 8; ++dt) {
            bf16x8 vf = *(const bf16x8*)&Vb[cb][(dt * 16 + m) * 32 + ((quad ^ ((m >> 1) & 3)) * 8)];
            o[dt] = __builtin_amdgcn_mfma_f32_16x16x32_bf16(pf, vf, o[dt], 0, 0, 0);
        }

        cb = (cb == 2) ? 0 : cb + 1;
    }
    #undef STAGE

    // partial row-sums: reduce li across the 16 lanes of each row group
    #pragma unroll
    for (int reg = 0; reg < 4; ++reg) {
        float t = li[reg];
        t += __shfl_xor(t, 1);
        t += __shfl_xor(t, 2);
        t += __shfl_xor(t, 4);
        t += __shfl_xor(t, 8);
        li[reg] = t;
    }
    const int rbase = q0 + wv * 16 + quad * 4;
    if (m == 0) {
        #pragma unroll
        for (int reg = 0; reg < 4; ++reg)
            Lpart[((size_t)ks * (BB * HH) + bh) * NN + rbase + reg] = li[reg];
    }
    // unnormalized partial O in fp16
    #pragma unroll
    for (int reg = 0; reg < 4; ++reg) {
        const size_t obase = (((size_t)ks * (BB * HH) + bh) * NN + rbase + reg) * DD;
        #pragma unroll
        for (int dt = 0; dt < 8; ++dt)
            Opart[obase + dt * 16 + m] = (_Float16)o[dt][reg];
    }
}

// ---------------- combine split-K partials -> Ocat bf16 ----------------
__global__ void combine_kernel(const _Float16* __restrict__ Op,
                               const float* __restrict__ Lp,
                               unsigned short* __restrict__ Ocat)
{
    const int SPLIT_OFF = BB * HH * NN * DD;   // 4,194,304
    int t = blockIdx.x * blockDim.x + threadIdx.x;   // 1,048,576 threads
    int e0 = t * 4;
    int row = e0 >> 7;                         // bh*N + n
    float l = 1.0f / (Lp[row] + Lp[row + BB * HH * NN]);
    f16x4 a = *(const f16x4*)(Op + e0);
    f16x4 c = *(const f16x4*)(Op + SPLIT_OFF + e0);
    int bh = row >> 11, n = row & (NN - 1);
    int b = bh >> 3, h = bh & 7;
    size_t obase = ((size_t)(b * NN + n)) * (HH * DD) + h * DD + (e0 & (DD - 1));
    unsigned short u[4];
    #pragma unroll
    for (int i = 0; i < 4; ++i)
        u[i] = f2bf(((float)a[i] + (float)c[i]) * l);
    *(ushort4*)(Ocat + obase) = *(ushort4*)u;
}

// ---------------- output projection: [4096 x 1024] @ [1024 x 256] + bout ----------------
__global__ __launch_bounds__(256) void out_kernel(
    const unsigned short* __restrict__ Ocat,
    const unsigned short* __restrict__ WoutT,   // [OUT][HD]
    const float* __restrict__ bout,
    float* __restrict__ out)
{
    const int m0 = blockIdx.x * 64;
    const int c0 = blockIdx.y * 64;
    const int tid = threadIdx.x;
    const int lane = tid & 63, wv = tid >> 6;
    const int m = lane & 15, quad = lane >> 4;

    __shared__ unsigned short Wlds[64 * 136];

    f32x4 acc[4];
    #pragma unroll
    for (int nt = 0; nt < 4; ++nt) acc[nt] = (f32x4){0.f, 0.f, 0.f, 0.f};

    const unsigned short* Orow = Ocat + (size_t)(m0 + wv * 16 + m) * (HH * DD);

    for (int kc = 0; kc < 8; ++kc) {
        #pragma unroll
        for (int i = tid; i < 64 * 16; i += 256) {
            int r = i >> 4, c = i & 15;
            *(uint4*)&Wlds[r * 136 + c * 8] =
                *(const uint4*)(WoutT + (size_t)(c0 + r) * (HH * DD) + kc * 128 + c * 8);
        }
        __syncthreads();
        #pragma unroll
        for (int j = 0; j < 4; ++j) {
            bf16x8 afr = *(const bf16x8*)(Orow + kc * 128 + j * 32 + quad * 8);
            #pragma unroll
            for (int nt = 0; nt < 4; ++nt) {
                bf16x8 bfr = *(const bf16x8*)&Wlds[(nt * 16 + m) * 136 + j * 32 + quad * 8];
                acc[nt] = __builtin_amdgcn_mfma_f32_16x16x32_bf16(afr, bfr, acc[nt], 0, 0, 0);
            }
        }
        __syncthreads();
    }

    #pragma unroll
    for (int nt = 0; nt < 4; ++nt) {
        int oc = c0 + nt * 16 + m;
        float bb = bout[oc];
        #pragma unroll
        for (int reg = 0; reg < 4; ++reg) {
            int r = m0 + wv * 16 + quad * 4 + reg;
            out[(size_t)r * OUTD + oc] = acc[nt][reg] + bb;
        }
    }
}

extern "C" void kernel_launch(void* const* d_in, const int* in_sizes, int n_in,
                              void* d_out, int out_size, void* d_ws, size_t ws_size,
                              hipStream_t stream)
{
    const float* X    = (const float*)d_in[0];
    const float* adj  = (const float*)d_in[1];
    const float* Wq   = (const float*)d_in[2];
    const float* bq   = (const float*)d_in[3];
    const float* Wk   = (const float*)d_in[4];
    const float* bk   = (const float*)d_in[5];
    const float* Wv   = (const float*)d_in[6];
    const float* bv   = (const float*)d_in[7];
    const float* Wout = (const float*)d_in[8];
    const float* bout = (const float*)d_in[9];
    float* out = (float*)d_out;

    char* ws = (char*)d_ws;
    unsigned short* Xb    = (unsigned short*)(ws);             // 1,048,576 B (dead after proj)
    unsigned short* WT    = (unsigned short*)(ws + 1048576);   //   786,432 B (dead after proj)
    unsigned short* WoutT = (unsigned short*)(ws + 1835008);   //   524,288 B
    unsigned short* Q     = (unsigned short*)(ws + 2359296);   // 8,388,608 B
    unsigned short* Kp    = (unsigned short*)(ws + 10747904);  // 8,388,608 B
    unsigned short* Vt    = (unsigned short*)(ws + 19136512);  // 8,388,608 B
    unsigned short* Ocat  = (unsigned short*)(ws + 27525120);  // 8,388,608 B
    unsigned short* AsumB = (unsigned short*)(ws + 35913728);  // 16,777,216 B
    _Float16*       Opart = (_Float16*)(ws + 52690944);        // 16,777,216 B (ends 69,468,160)
    float*          Lpart = (float*)(ws);                      // 262,144 B, reuses dead Xb region

    prep_kernel<<<4608, 256, 0, stream>>>(X, Wq, Wk, Wv, Wout, Xb, WT, WoutT);
    adjsum_kernel<<<(BB * NN * NN) / 256, 256, 0, stream>>>((const float4*)adj, AsumB);
    proj_kernel<<<dim3(NN / 64, BB * HH, 3), 256, 0, stream>>>(Xb, WT, bq, bk, bv, Q, Kp, Vt);
    attn_kernel<<<dim3(128, HH), 256, 0, stream>>>(Q, Kp, Vt, AsumB, Opart, Lpart);
    combine_kernel<<<(BB * HH * NN * DD / 4) / 256, 256, 0, stream>>>(Opart, Lpart, Ocat);
    out_kernel<<<dim3((BB * NN) / 64, OUTD / 64), 256, 0, stream>>>(Ocat, WoutT, bout, out);
}

// Round 7
// 310.471 us; speedup vs baseline: 1.1249x; 1.0507x over previous
//
#include <hip/hip_runtime.h>
#include <hip/hip_bf16.h>

#define BB 2
#define NN 2048
#define DD 128
#define HH 8
#define OUTD 256
#define SCALE 0.022097086912079612f  // 1/sqrt(2048)

typedef __bf16 bf16x8 __attribute__((ext_vector_type(8)));
typedef float f32x4 __attribute__((ext_vector_type(4)));
typedef _Float16 f16x8 __attribute__((ext_vector_type(8)));

__device__ __forceinline__ unsigned short f2bf(float f) {
    union { float f; unsigned int u; } v; v.f = f;
    unsigned int r = (v.u + 0x7FFFu + ((v.u >> 16) & 1u)) >> 16;
    return (unsigned short)r;
}
__device__ __forceinline__ float bf2f(unsigned short s) {
    union { unsigned int u; float f; } v; v.u = ((unsigned int)s) << 16;
    return v.f;
}
// async global->LDS, 16 B per lane; lds dst = wave-uniform base + lane*16
__device__ __forceinline__ void gl_lds16(const unsigned short* g, unsigned short* l) {
    __builtin_amdgcn_global_load_lds(
        (const __attribute__((address_space(1))) unsigned int*)g,
        (__attribute__((address_space(3))) unsigned int*)l,
        16, 0, 0);
}

// ---------------- prep: bf16 casts + weight transposes ----------------
__global__ void prep_kernel(const float* __restrict__ X,
                            const float* __restrict__ Wq,
                            const float* __restrict__ Wk,
                            const float* __restrict__ Wv,
                            const float* __restrict__ Wout,
                            unsigned short* __restrict__ Xb,     // [B][N][D]
                            unsigned short* __restrict__ WT,     // [3][H][e][d]
                            unsigned short* __restrict__ WoutT)  // [OUT][H*D]
{
    const int NX  = BB * NN * DD;        // 524288
    const int NW  = 3 * HH * DD * DD;    // 393216
    const int NWO = (HH * DD) * OUTD;    // 262144
    int idx = blockIdx.x * blockDim.x + threadIdx.x;
    if (idx < NX) {
        Xb[idx] = f2bf(X[idx]);
    } else if (idx < NX + NW) {
        int i = idx - NX;
        int mat = i / (HH * DD * DD);
        int r   = i % (HH * DD * DD);
        int h = r / (DD * DD);
        int j = r % (DD * DD);
        int e = j / DD;
        int d = j % DD;
        const float* Wm = (mat == 0) ? Wq : ((mat == 1) ? Wk : Wv);
        WT[i] = f2bf(Wm[h * DD * DD + d * DD + e]);
    } else if (idx < NX + NW + NWO) {
        int i = idx - NX - NW;
        int o = i / (HH * DD);
        int k = i % (HH * DD);
        WoutT[i] = f2bf(Wout[k * OUTD + o]);
    }
}

// ---------------- adjsum: nodeadj.sum(-1) -> bf16 ----------------
__global__ void adjsum_kernel(const float4* __restrict__ adj, unsigned short* __restrict__ s) {
    int idx = blockIdx.x * blockDim.x + threadIdx.x;  // B*N*N threads
    float4 a = adj[idx];
    s[idx] = f2bf((a.x + a.y) + (a.z + a.w));
}

// ---------------- projections q/k/v ----------------
// grid (N/64, B*H, 3); block 256. mat: 0=Q, 1=K, 2=V(transposed output via LDS)
__global__ __launch_bounds__(256) void proj_kernel(
    const unsigned short* __restrict__ Xb,
    const unsigned short* __restrict__ WT,
    const float* __restrict__ bq, const float* __restrict__ bk, const float* __restrict__ bv,
    unsigned short* __restrict__ Qo, unsigned short* __restrict__ Ko,
    unsigned short* __restrict__ Vt)
{
    const int mat = blockIdx.z;
    const int bh  = blockIdx.y;
    const int b = bh >> 3, h = bh & 7;
    const int n0 = blockIdx.x * 64;
    const int tid = threadIdx.x;
    const int lane = tid & 63, wv = tid >> 6;
    const int m = lane & 15, quad = lane >> 4;

    __shared__ unsigned short Wlds[128 * 136];  // [e][d], pad 136; reused for V transpose

    const unsigned short* Wg = WT + ((size_t)mat * HH + h) * (DD * DD);
    #pragma unroll
    for (int i = tid; i < 128 * 16; i += 256) {
        int r = i >> 4, c = i & 15;
        *(uint4*)&Wlds[r * 136 + c * 8] = *(const uint4*)(Wg + r * 128 + c * 8);
    }

    const int row = n0 + wv * 16 + m;
    const unsigned short* Xr = Xb + ((size_t)b * NN + row) * DD;
    bf16x8 af[4];
    #pragma unroll
    for (int kc = 0; kc < 4; ++kc)
        af[kc] = *(const bf16x8*)(Xr + kc * 32 + quad * 8);

    __syncthreads();

    f32x4 acc[8];
    #pragma unroll
    for (int et = 0; et < 8; ++et) acc[et] = (f32x4){0.f, 0.f, 0.f, 0.f};

    #pragma unroll
    for (int kc = 0; kc < 4; ++kc) {
        #pragma unroll
        for (int et = 0; et < 8; ++et) {
            bf16x8 bfrg = *(const bf16x8*)&Wlds[(et * 16 + m) * 136 + kc * 32 + quad * 8];
            acc[et] = __builtin_amdgcn_mfma_f32_16x16x32_bf16(af[kc], bfrg, acc[et], 0, 0, 0);
        }
    }

    const float* bias = (mat == 0) ? bq : ((mat == 1) ? bk : bv);
    if (mat != 2) {
        #pragma unroll
        for (int et = 0; et < 8; ++et) {
            int e = et * 16 + m;
            float bb = bias[h * DD + e];
            #pragma unroll
            for (int reg = 0; reg < 4; ++reg) {
                int r = n0 + wv * 16 + quad * 4 + reg;
                unsigned short v16 = f2bf(acc[et][reg] + bb);
                if (mat == 0) Qo[((size_t)bh * NN + r) * DD + e] = v16;
                else          Ko[((size_t)bh * NN + r) * DD + e] = v16;
            }
        }
    } else {
        // V: transpose through LDS -> coalesced uint4 stores to Vt[bh][e][n]
        __syncthreads();  // everyone done with Wlds MFMA reads
        #pragma unroll
        for (int et = 0; et < 8; ++et) {
            int e = et * 16 + m;
            float bb = bias[h * DD + e];
            #pragma unroll
            for (int reg = 0; reg < 4; ++reg)
                Wlds[(wv * 16 + quad * 4 + reg) * 136 + e] = f2bf(acc[et][reg] + bb);
        }
        __syncthreads();
        const int e = tid >> 1, nh = tid & 1;
        #pragma unroll
        for (int j = 0; j < 4; ++j) {
            unsigned short tmp[8];
            #pragma unroll
            for (int kk = 0; kk < 8; ++kk)
                tmp[kk] = Wlds[(nh * 32 + j * 8 + kk) * 136 + e];
            *(uint4*)(Vt + ((size_t)bh * DD + e) * NN + n0 + nh * 32 + j * 8) = *(uint4*)tmp;
        }
    }
}

// ---------------- flash attention, split-K x2, async LDS staging ----------------
// R0-verbatim schedule: 16 q-rows/wave, 4 waves/block, 4 blocks/CU, TK=32,
// 2-buffer K/V via global_load_lds, __syncthreads per kt. All R1-R5 schedule
// variants (32-row waves, vectorized adj, 3-buffer counted vmcnt) measured
// slower: at 4 blocks/CU the inter-block wave overlap already hides the
// barrier drain, and every variant paid occupancy for its mechanism.
// grid (128, 8): x = ((b*32 + qt)*2 + ks), y = h  (h-siblings share XCD)
__global__ __launch_bounds__(256, 4) void attn_kernel(
    const unsigned short* __restrict__ Q,
    const unsigned short* __restrict__ K,
    const unsigned short* __restrict__ Vt,
    const unsigned short* __restrict__ adjs,   // bf16 [B][N][N]
    _Float16* __restrict__ Opart,              // [2][BH][N][D] fp16 partials
    float* __restrict__ Lpart)                 // [2][BH][N] fp32 partial row-sums
{
    const int x = blockIdx.x;
    const int h = blockIdx.y;
    const int ks = x & 1, qt = (x >> 1) & 31, b = x >> 6;
    const int bh = b * HH + h;
    const int q0 = qt * 64;
    const int kstart = ks * 1024;
    const int tid = threadIdx.x;
    const int lane = tid & 63, wv = tid >> 6;
    const int m = lane & 15, quad = lane >> 4;

    __shared__ unsigned short Kb[2][32 * 128];   // [key][d] swizzled, 8 KB each
    __shared__ unsigned short Vb[2][128 * 32];   // [d][key] swizzled, 8 KB each
    __shared__ unsigned short Plds[4][16 * 40];  // per-wave P, pad 40 -> 5 KB
    // total 37.9 KB -> 4 blocks/CU

    const unsigned short* Kbase = K + (size_t)bh * NN * DD;
    const unsigned short* Vbase = Vt + (size_t)bh * DD * NN;

    // Q fragments (register-resident for whole kernel)
    const int qrow = q0 + wv * 16 + m;
    const unsigned short* Qr = Q + ((size_t)bh * NN + qrow) * DD;
    bf16x8 qf[4];
    #pragma unroll
    for (int kc = 0; kc < 4; ++kc)
        qf[kc] = *(const bf16x8*)(Qr + kc * 32 + quad * 8);

    f32x4 o[8];
    #pragma unroll
    for (int dt = 0; dt < 8; ++dt) o[dt] = (f32x4){0.f, 0.f, 0.f, 0.f};
    float li[4] = {0.f, 0.f, 0.f, 0.f};

    const unsigned short* Abase = adjs + ((size_t)b * NN + q0 + wv * 16 + quad * 4) * NN;

    // staging lane decomposition
    const int kr4 = lane >> 4, kc16 = lane & 15;  // K: 4 rows x 16 chunks / instr
    const int vr16 = lane >> 2, vc4 = lane & 3;   // V: 16 rows x 4 chunks / instr

    // each wave stages K-instrs {2w,2w+1} (rows 8w..8w+7) and V-instrs {2w,2w+1} (d rows 32w..32w+31)
    #define STAGE(buf, kbase_)                                                              \
        {                                                                                   \
            _Pragma("unroll")                                                               \
            for (int j2 = 0; j2 < 2; ++j2) {                                                \
                const int j = wv * 2 + j2;                                                  \
                const int krow = j * 4 + kr4;                                               \
                gl_lds16(Kbase + (size_t)((kbase_) + krow) * DD + ((kc16 ^ (krow & 15)) * 8),\
                         &Kb[buf][j * 512]);                                                \
                const int vrow = j * 16 + vr16;                                             \
                gl_lds16(Vbase + (size_t)vrow * NN + (kbase_) + ((vc4 ^ ((vr16 >> 1) & 3)) * 8),\
                         &Vb[buf][j * 512]);                                                \
            }                                                                               \
        }

    STAGE(0, kstart);
    __syncthreads();   // vmcnt drain -> tile 0 ready

    for (int kt = 0; kt < 32; ++kt) {
        const int cb = kt & 1, nb = cb ^ 1;
        const int k0 = kstart + kt * 32;

        // adj (bf16) for current tile, per-lane scalar loads (consumed after QK)
        float areg[2][4];
        #pragma unroll
        for (int nt = 0; nt < 2; ++nt)
            #pragma unroll
            for (int reg = 0; reg < 4; ++reg)
                areg[nt][reg] = bf2f(Abase[(size_t)reg * NN + k0 + nt * 16 + m]) * SCALE;

        // async-stage next tile (no wait here; barrier at loop end drains)
        if (kt + 1 < 32) STAGE(nb, k0 + 32);

        // QK^T : 8 MFMA
        f32x4 s[2];
        s[0] = (f32x4){0.f, 0.f, 0.f, 0.f};
        s[1] = (f32x4){0.f, 0.f, 0.f, 0.f};
        #pragma unroll
        for (int kc = 0; kc < 4; ++kc) {
            #pragma unroll
            for (int nt = 0; nt < 2; ++nt) {
                bf16x8 kf = *(const bf16x8*)&Kb[cb][(nt * 16 + m) * 128 + (((kc * 4 + quad) ^ m) * 8)];
                s[nt] = __builtin_amdgcn_mfma_f32_16x16x32_bf16(qf[kc], kf, s[nt], 0, 0, 0);
            }
        }

        // p = exp(s*scale*adj)  (no max subtraction: |s*a| < ~1)
        #pragma unroll
        for (int nt = 0; nt < 2; ++nt) {
            #pragma unroll
            for (int reg = 0; reg < 4; ++reg) {
                float p = __expf(s[nt][reg] * areg[nt][reg]);
                li[reg] += p;
                Plds[wv][(quad * 4 + reg) * 40 + nt * 16 + m] = f2bf(p);
            }
        }

        // P x V : 8 MFMA (K=32 covers full tile)
        bf16x8 pf = *(const bf16x8*)&Plds[wv][m * 40 + quad * 8];
        #pragma unroll
        for (int dt = 0; dt < 8; ++dt) {
            bf16x8 vf = *(const bf16x8*)&Vb[cb][(dt * 16 + m) * 32 + ((quad ^ ((m >> 1) & 3)) * 8)];
            o[dt] = __builtin_amdgcn_mfma_f32_16x16x32_bf16(pf, vf, o[dt], 0, 0, 0);
        }

        __syncthreads();  // readers done with cb; stage(nb) drained (vmcnt0 at barrier)
    }
    #undef STAGE

    // partial row-sums: reduce li across the 16 lanes of each row group
    #pragma unroll
    for (int reg = 0; reg < 4; ++reg) {
        float t = li[reg];
        t += __shfl_xor(t, 1);
        t += __shfl_xor(t, 2);
        t += __shfl_xor(t, 4);
        t += __shfl_xor(t, 8);
        li[reg] = t;
    }
    const int rbase = q0 + wv * 16 + quad * 4;
    if (m == 0) {
        #pragma unroll
        for (int reg = 0; reg < 4; ++reg)
            Lpart[((size_t)ks * (BB * HH) + bh) * NN + rbase + reg] = li[reg];
    }
    // unnormalized partial O in fp16
    #pragma unroll
    for (int reg = 0; reg < 4; ++reg) {
        const size_t obase = (((size_t)ks * (BB * HH) + bh) * NN + rbase + reg) * DD;
        #pragma unroll
        for (int dt = 0; dt < 8; ++dt)
            Opart[obase + dt * 16 + m] = (_Float16)o[dt][reg];
    }
}

// ---------------- fused combine + output projection ----------------
// A-fragments computed on the fly from split-K partials: a = f2bf((o0+o1)*l)
// — bit-identical to the old combine_kernel, so absmax is unchanged. Kills
// the combine launch, the 8.4 MB Ocat write and its re-reads. Opart re-reads
// across c0-blocks stay on one XCD (grid y-stride 64 ≡ 0 mod 8) -> L2 hits.
// grid ((B*N)/64, OUT/64); block 256.
__global__ __launch_bounds__(256) void out_kernel(
    const _Float16* __restrict__ Op,        // [2][BH][N][D] fp16 partials
    const float* __restrict__ Lp,           // [2][BH][N]
    const unsigned short* __restrict__ WoutT,   // [OUT][HD]
    const float* __restrict__ bout,
    float* __restrict__ out)
{
    const int SPLIT_OFF = BB * HH * NN * DD;   // 4,194,304 (f16 elems)
    const int m0 = blockIdx.x * 64;
    const int c0 = blockIdx.y * 64;
    const int tid = threadIdx.x;
    const int lane = tid & 63, wv = tid >> 6;
    const int m = lane & 15, quad = lane >> 4;

    __shared__ unsigned short Wlds[64 * 136];

    f32x4 acc[4];
    #pragma unroll
    for (int nt = 0; nt < 4; ++nt) acc[nt] = (f32x4){0.f, 0.f, 0.f, 0.f};

    const int r = m0 + wv * 16 + m;        // A-row this lane reads
    const int b = r >> 11, n = r & (NN - 1);

    for (int kc = 0; kc < 8; ++kc) {       // kc == head h
        #pragma unroll
        for (int i = tid; i < 64 * 16; i += 256) {
            int rr = i >> 4, c = i & 15;
            *(uint4*)&Wlds[rr * 136 + c * 8] =
                *(const uint4*)(WoutT + (size_t)(c0 + rr) * (HH * DD) + kc * 128 + c * 8);
        }
        __syncthreads();

        const int bh = b * HH + kc;
        const float l = 1.0f / (Lp[bh * NN + n] + Lp[BB * HH * NN + bh * NN + n]);
        const _Float16* pa = Op + ((size_t)bh * NN + n) * DD;

        #pragma unroll
        for (int j = 0; j < 4; ++j) {
            f16x8 va = *(const f16x8*)(pa + j * 32 + quad * 8);
            f16x8 vc = *(const f16x8*)(pa + SPLIT_OFF + j * 32 + quad * 8);
            unsigned short uu[8];
            #pragma unroll
            for (int i = 0; i < 8; ++i)
                uu[i] = f2bf(((float)va[i] + (float)vc[i]) * l);
            bf16x8 afr = *(const bf16x8*)uu;
            #pragma unroll
            for (int nt = 0; nt < 4; ++nt) {
                bf16x8 bfr = *(const bf16x8*)&Wlds[(nt * 16 + m) * 136 + j * 32 + quad * 8];
                acc[nt] = __builtin_amdgcn_mfma_f32_16x16x32_bf16(afr, bfr, acc[nt], 0, 0, 0);
            }
        }
        __syncthreads();
    }

    #pragma unroll
    for (int nt = 0; nt < 4; ++nt) {
        int oc = c0 + nt * 16 + m;
        float bb = bout[oc];
        #pragma unroll
        for (int reg = 0; reg < 4; ++reg) {
            int rr = m0 + wv * 16 + quad * 4 + reg;
            out[(size_t)rr * OUTD + oc] = acc[nt][reg] + bb;
        }
    }
}

extern "C" void kernel_launch(void* const* d_in, const int* in_sizes, int n_in,
                              void* d_out, int out_size, void* d_ws, size_t ws_size,
                              hipStream_t stream)
{
    const float* X    = (const float*)d_in[0];
    const float* adj  = (const float*)d_in[1];
    const float* Wq   = (const float*)d_in[2];
    const float* bq   = (const float*)d_in[3];
    const float* Wk   = (const float*)d_in[4];
    const float* bk   = (const float*)d_in[5];
    const float* Wv   = (const float*)d_in[6];
    const float* bv   = (const float*)d_in[7];
    const float* Wout = (const float*)d_in[8];
    const float* bout = (const float*)d_in[9];
    float* out = (float*)d_out;

    char* ws = (char*)d_ws;
    unsigned short* Xb    = (unsigned short*)(ws);             // 1,048,576 B (dead after proj)
    unsigned short* WT    = (unsigned short*)(ws + 1048576);   //   786,432 B (dead after proj)
    unsigned short* WoutT = (unsigned short*)(ws + 1835008);   //   524,288 B
    unsigned short* Q     = (unsigned short*)(ws + 2359296);   // 8,388,608 B
    unsigned short* Kp    = (unsigned short*)(ws + 10747904);  // 8,388,608 B
    unsigned short* Vt    = (unsigned short*)(ws + 19136512);  // 8,388,608 B
    unsigned short* AsumB = (unsigned short*)(ws + 35913728);  // 16,777,216 B
    _Float16*       Opart = (_Float16*)(ws + 52690944);        // 16,777,216 B (ends 69,468,160)
    float*          Lpart = (float*)(ws);                      // 262,144 B, reuses dead Xb region

    prep_kernel<<<4608, 256, 0, stream>>>(X, Wq, Wk, Wv, Wout, Xb, WT, WoutT);
    adjsum_kernel<<<(BB * NN * NN) / 256, 256, 0, stream>>>((const float4*)adj, AsumB);
    proj_kernel<<<dim3(NN / 64, BB * HH, 3), 256, 0, stream>>>(Xb, WT, bq, bk, bv, Q, Kp, Vt);
    attn_kernel<<<dim3(128, HH), 256, 0, stream>>>(Q, Kp, Vt, AsumB, Opart, Lpart);
    out_kernel<<<dim3((BB * NN) / 64, OUTD / 64), 256, 0, stream>>>(Opart, Lpart, WoutT, bout, out);
}